// Round 2
// baseline (1439.069 us; speedup 1.0000x reference)
//
#include <hip/hip_runtime.h>
#include <cstdint>

// ---------------------------------------------------------------------------
// RegionModel: per-sample 3-layer CNN expert (region-gathered weights)
//   conv1: 3->32,  256->128, 3x3 s2 p1, bias+ReLU
//   conv2: 32->64, 128->64
//   conv3: 64->128, 64->32, then GAP(32x32) and 2x128 linear head
// R2: same fp32 direct-conv structure as R1 (one thread = one output pixel,
// all out-channels in registers, wave-uniform weight reads, LDS input tile),
// but (a) batch is processed in chunks sized to fit ws_size (R1 assumed
// ~404 MB of scratch and likely overran d_ws -> device fault / SIGABRT),
// (b) no hipMemsetAsync inside kernel_launch (feat zeroed by prep kernel).
// ---------------------------------------------------------------------------

__global__ __launch_bounds__(128) void prep_k(const int* __restrict__ rp,
                                              int* __restrict__ rout,
                                              float* __restrict__ feat) {
  // Defensive: region may be stored int64 (values 0..7 -> odd int32 words 0).
  __shared__ int is64;
  if (threadIdx.x == 0) {
    int odd_or = 0;
    for (int i = 0; i < 64; ++i) odd_or |= rp[2 * i + 1];
    is64 = (odd_or == 0) ? 1 : 0;
  }
  __syncthreads();
  int b = threadIdx.x;
  int r = is64 ? rp[2 * b] : rp[b];
  rout[b] = r & 7;
  // zero the GAP accumulator (conv3 atomically adds into it)
  float* fr = feat + b * 128;
  for (int j = 0; j < 128; ++j) fr[j] = 0.f;
}

// dst[r][k][oc] = src[r][oc][k]
__global__ __launch_bounds__(256) void repack_k(const float* __restrict__ src,
                                                float* __restrict__ dst,
                                                int OC, int K, int total) {
  int i = blockIdx.x * blockDim.x + threadIdx.x;
  if (i >= total) return;
  int ock = OC * K;
  int r = i / ock;
  int rem = i - r * ock;
  int oc = rem / K;
  int k = rem - oc * K;
  dst[(r * K + k) * OC + oc] = src[i];
}

__global__ __launch_bounds__(256) void conv1_k(
    const float* __restrict__ img, const float* __restrict__ wT,
    const float* __restrict__ bias, const int* __restrict__ rgn,
    float* __restrict__ h1, int b0) {
  const int bl = blockIdx.z;
  const int b = b0 + bl;
  const int r = __builtin_amdgcn_readfirstlane(rgn[b]);
  const int oy0 = blockIdx.y * 16, ox0 = blockIdx.x * 16;
  const int tid = threadIdx.x;
  const int ty = tid >> 4, tx = tid & 15;
  __shared__ float lds[3 * 33 * 34];
  const int iy0 = 2 * oy0 - 1, ix0 = 2 * ox0 - 1;
  for (int idx = tid; idx < 3 * 33 * 33; idx += 256) {
    int c = idx / 1089;
    int rem = idx - c * 1089;
    int yy = rem / 33;
    int xx = rem - yy * 33;
    int iy = iy0 + yy, ix = ix0 + xx;
    float v = 0.f;
    if ((unsigned)iy < 256u && (unsigned)ix < 256u)
      v = img[((b * 3 + c) * 256 + iy) * 256 + ix];
    lds[(c * 33 + yy) * 34 + xx] = v;
  }
  __syncthreads();
  float acc[32];
#pragma unroll
  for (int oc = 0; oc < 32; ++oc) acc[oc] = 0.f;
  const float* wr = wT + r * 27 * 32;
#pragma unroll
  for (int c = 0; c < 3; ++c)
#pragma unroll
    for (int ky = 0; ky < 3; ++ky)
#pragma unroll
      for (int kx = 0; kx < 3; ++kx) {
        float iv = lds[(c * 33 + 2 * ty + ky) * 34 + 2 * tx + kx];
        const float* wk = wr + ((c * 3 + ky) * 3 + kx) * 32;
#pragma unroll
        for (int oc = 0; oc < 32; ++oc) acc[oc] = fmaf(iv, wk[oc], acc[oc]);
      }
  const int oy = oy0 + ty, ox = ox0 + tx;
  const float* br = bias + r * 32;
#pragma unroll
  for (int oc = 0; oc < 32; ++oc) {
    float v = acc[oc] + br[oc];
    h1[((bl * 32 + oc) * 128 + oy) * 128 + ox] = v > 0.f ? v : 0.f;
  }
}

__global__ __launch_bounds__(256) void conv2_k(
    const float* __restrict__ h1, const float* __restrict__ wT,
    const float* __restrict__ bias, const int* __restrict__ rgn,
    float* __restrict__ h2, int b0) {
  const int bl = blockIdx.z;
  const int b = b0 + bl;
  const int r = __builtin_amdgcn_readfirstlane(rgn[b]);
  const int oy0 = blockIdx.y * 16, ox0 = blockIdx.x * 16;
  const int tid = threadIdx.x;
  const int ty = tid >> 4, tx = tid & 15;
  __shared__ float lds[33 * 34];
  const int iy0 = 2 * oy0 - 1, ix0 = 2 * ox0 - 1;
  float acc[64];
#pragma unroll
  for (int oc = 0; oc < 64; ++oc) acc[oc] = 0.f;
  const float* wr = wT + r * 288 * 64;
  for (int ic = 0; ic < 32; ++ic) {
    __syncthreads();
    const float* sp = h1 + (size_t)(bl * 32 + ic) * 128 * 128;
    for (int idx = tid; idx < 33 * 33; idx += 256) {
      int yy = idx / 33, xx = idx - yy * 33;
      int iy = iy0 + yy, ix = ix0 + xx;
      float v = 0.f;
      if ((unsigned)iy < 128u && (unsigned)ix < 128u) v = sp[iy * 128 + ix];
      lds[yy * 34 + xx] = v;
    }
    __syncthreads();
#pragma unroll
    for (int ky = 0; ky < 3; ++ky)
#pragma unroll
      for (int kx = 0; kx < 3; ++kx) {
        float iv = lds[(2 * ty + ky) * 34 + 2 * tx + kx];
        const float* wk = wr + (ic * 9 + ky * 3 + kx) * 64;
#pragma unroll
        for (int oc = 0; oc < 64; ++oc) acc[oc] = fmaf(iv, wk[oc], acc[oc]);
      }
  }
  const int oy = oy0 + ty, ox = ox0 + tx;
  const float* br = bias + r * 64;
#pragma unroll
  for (int oc = 0; oc < 64; ++oc) {
    float v = acc[oc] + br[oc];
    h2[((bl * 64 + oc) * 64 + oy) * 64 + ox] = v > 0.f ? v : 0.f;
  }
}

__global__ __launch_bounds__(256) void conv3_k(
    const float* __restrict__ h2, const float* __restrict__ wT,
    const float* __restrict__ bias, const int* __restrict__ rgn,
    float* __restrict__ feat, int b0) {
  const int bl = blockIdx.z;
  const int b = b0 + bl;
  const int r = __builtin_amdgcn_readfirstlane(rgn[b]);
  const int tile = blockIdx.x;      // 0..3 -> 2x2 tiles of 16x16 over 32x32
  const int oc0 = blockIdx.y * 64;  // 0 or 64
  const int oy0 = (tile >> 1) * 16, ox0 = (tile & 1) * 16;
  const int tid = threadIdx.x;
  const int ty = tid >> 4, tx = tid & 15;
  __shared__ float lds[33 * 34];
  const int iy0 = 2 * oy0 - 1, ix0 = 2 * ox0 - 1;
  float acc[64];
#pragma unroll
  for (int oc = 0; oc < 64; ++oc) acc[oc] = 0.f;
  const float* wr = wT + r * 576 * 128;
  for (int ic = 0; ic < 64; ++ic) {
    __syncthreads();
    const float* sp = h2 + (size_t)(bl * 64 + ic) * 64 * 64;
    for (int idx = tid; idx < 33 * 33; idx += 256) {
      int yy = idx / 33, xx = idx - yy * 33;
      int iy = iy0 + yy, ix = ix0 + xx;
      float v = 0.f;
      if ((unsigned)iy < 64u && (unsigned)ix < 64u) v = sp[iy * 64 + ix];
      lds[yy * 34 + xx] = v;
    }
    __syncthreads();
#pragma unroll
    for (int ky = 0; ky < 3; ++ky)
#pragma unroll
      for (int kx = 0; kx < 3; ++kx) {
        float iv = lds[(2 * ty + ky) * 34 + 2 * tx + kx];
        const float* wk = wr + (ic * 9 + ky * 3 + kx) * 128 + oc0;
#pragma unroll
        for (int oc = 0; oc < 64; ++oc) acc[oc] = fmaf(iv, wk[oc], acc[oc]);
      }
  }
  // bias + ReLU + partial global-average-pool reduce
  __syncthreads();
  const float* br = bias + r * 128 + oc0;
  const int wave = tid >> 6, lane = tid & 63;
#pragma unroll
  for (int oc = 0; oc < 64; ++oc) {
    float v = acc[oc] + br[oc];
    v = v > 0.f ? v : 0.f;
#pragma unroll
    for (int off = 32; off > 0; off >>= 1) v += __shfl_down(v, off, 64);
    if (lane == 0) lds[oc * 4 + wave] = v;
  }
  __syncthreads();
  if (tid < 64) {
    float s = lds[tid * 4] + lds[tid * 4 + 1] + lds[tid * 4 + 2] + lds[tid * 4 + 3];
    atomicAdd(&feat[b * 128 + oc0 + tid], s);
  }
}

__global__ __launch_bounds__(256) void head_k(
    const float* __restrict__ feat, const float* __restrict__ fw,
    const float* __restrict__ fb, const int* __restrict__ rgn,
    float* __restrict__ out) {
  int t = threadIdx.x;  // 256 = 128 samples x 2 classes
  int b = t >> 1, c = t & 1;
  int r = rgn[b];
  const float* fwr = fw + (r * 2 + c) * 128;
  const float* fv = feat + b * 128;
  float a = 0.f;
#pragma unroll 8
  for (int j = 0; j < 128; ++j) a = fmaf(fwr[j], fv[j], a);
  out[t] = a * (1.0f / 1024.0f) + fb[r * 2 + c];
}

extern "C" void kernel_launch(void* const* d_in, const int* in_sizes, int n_in,
                              void* d_out, int out_size, void* d_ws, size_t ws_size,
                              hipStream_t stream) {
  const float* img = (const float*)d_in[0];
  const int* rgn_raw = (const int*)d_in[1];
  const float* w1 = (const float*)d_in[2];
  const float* b1 = (const float*)d_in[3];
  const float* w2 = (const float*)d_in[4];
  const float* b2 = (const float*)d_in[5];
  const float* w3 = (const float*)d_in[6];
  const float* b3 = (const float*)d_in[7];
  const float* fw = (const float*)d_in[8];
  const float* fb = (const float*)d_in[9];
  float* out = (float*)d_out;

  // --- workspace budget ---------------------------------------------------
  const size_t h1s = (size_t)32 * 128 * 128 * 4;  // 2 MB per sample
  const size_t h2s = (size_t)64 * 64 * 64 * 4;    // 1 MB per sample
  const size_t fixed = ((size_t)8 * 27 * 32 + (size_t)8 * 288 * 64 +
                        (size_t)8 * 576 * 128 + 128 * 128 + 128) * 4 +
                       8 * 256;  // tables + feat + rgn + alignment slop
  int C = 128;  // batch chunk (power of two, divides 128)
  while (C > 1 && fixed + (size_t)C * (h1s + h2s) > ws_size) C >>= 1;

  char* ws = (char*)d_ws;
  size_t off = 0;
  auto alloc = [&](size_t bytes) {
    char* p = ws + off;
    off += (bytes + 255) & ~(size_t)255;
    return p;
  };
  float* h1 = (float*)alloc((size_t)C * h1s);
  float* h2 = (float*)alloc((size_t)C * h2s);
  float* wT1 = (float*)alloc((size_t)8 * 27 * 32 * 4);
  float* wT2 = (float*)alloc((size_t)8 * 288 * 64 * 4);
  float* wT3 = (float*)alloc((size_t)8 * 576 * 128 * 4);
  float* feat = (float*)alloc((size_t)128 * 128 * 4);
  int* rgn = (int*)alloc((size_t)128 * 4);

  hipLaunchKernelGGL(prep_k, dim3(1), dim3(128), 0, stream, rgn_raw, rgn, feat);
  hipLaunchKernelGGL(repack_k, dim3((8 * 32 * 27 + 255) / 256), dim3(256), 0, stream,
                     w1, wT1, 32, 27, 8 * 32 * 27);
  hipLaunchKernelGGL(repack_k, dim3((8 * 64 * 288 + 255) / 256), dim3(256), 0, stream,
                     w2, wT2, 64, 288, 8 * 64 * 288);
  hipLaunchKernelGGL(repack_k, dim3((8 * 128 * 576 + 255) / 256), dim3(256), 0, stream,
                     w3, wT3, 128, 576, 8 * 128 * 576);

  for (int b0 = 0; b0 < 128; b0 += C) {
    hipLaunchKernelGGL(conv1_k, dim3(8, 8, C), dim3(256), 0, stream, img, wT1, b1, rgn, h1, b0);
    hipLaunchKernelGGL(conv2_k, dim3(4, 4, C), dim3(256), 0, stream, h1, wT2, b2, rgn, h2, b0);
    hipLaunchKernelGGL(conv3_k, dim3(4, 2, C), dim3(256), 0, stream, h2, wT3, b3, rgn, feat, b0);
  }
  hipLaunchKernelGGL(head_k, dim3(1), dim3(256), 0, stream, feat, fw, fb, rgn, out);
}

// Round 4
// 1196.532 us; speedup vs baseline: 1.2027x; 1.2027x over previous
//
#include <hip/hip_runtime.h>
#include <cstdint>

// ---------------------------------------------------------------------------
// RegionModel: per-sample 3-layer CNN expert (region-gathered weights)
//   conv1: 3->32,  256->128, 3x3 s2 p1, bias+ReLU
//   conv2: 32->64, 128->64
//   conv3: 64->128, 64->32, then GAP(32x32) and 2x128 linear head
// R4 = R3's kernels (acc[32]/thread so accumulators stay in VGPRs --
// R2's acc[64] compiled to VGPR_Count=40 with AGPR round-trips; 4-ic LDS
// staging; __launch_bounds__(256,4)) + R2's ws_size-adaptive batch chunking.
// R1/R3 both SIGABRT'd by assuming ~406 MB of d_ws; R2 passed by adapting.
// C depends only on ws_size -> identical launch sequence per call (graph-safe).
// ---------------------------------------------------------------------------

__global__ __launch_bounds__(128) void prep_k(const int* __restrict__ rp,
                                              int* __restrict__ rout,
                                              float* __restrict__ feat) {
  // Defensive: region may be stored int64 (values 0..7 -> odd int32 words 0).
  __shared__ int is64;
  if (threadIdx.x == 0) {
    int odd_or = 0;
    for (int i = 0; i < 64; ++i) odd_or |= rp[2 * i + 1];
    is64 = (odd_or == 0) ? 1 : 0;
  }
  __syncthreads();
  int b = threadIdx.x;
  int r = is64 ? rp[2 * b] : rp[b];
  rout[b] = r & 7;
  // zero the GAP accumulator (conv3 atomically adds into it)
  float* fr = feat + b * 128;
  for (int j = 0; j < 128; ++j) fr[j] = 0.f;
}

// dst[r][k][oc] = src[r][oc][k]
__global__ __launch_bounds__(256) void repack_k(const float* __restrict__ src,
                                                float* __restrict__ dst,
                                                int OC, int K, int total) {
  int i = blockIdx.x * blockDim.x + threadIdx.x;
  if (i >= total) return;
  int ock = OC * K;
  int r = i / ock;
  int rem = i - r * ock;
  int oc = rem / K;
  int k = rem - oc * K;
  dst[(r * K + k) * OC + oc] = src[i];
}

__global__ __launch_bounds__(256, 4) void conv1_k(
    const float* __restrict__ img, const float* __restrict__ wT,
    const float* __restrict__ bias, const int* __restrict__ rgn,
    float* __restrict__ h1, int b0) {
  const int bl = blockIdx.z;
  const int b = b0 + bl;
  const int r = __builtin_amdgcn_readfirstlane(rgn[b]);
  const int oy0 = blockIdx.y * 16, ox0 = blockIdx.x * 16;
  const int tid = threadIdx.x;
  const int ty = tid >> 4, tx = tid & 15;
  __shared__ float lds[3 * 33 * 34];
  const int iy0 = 2 * oy0 - 1, ix0 = 2 * ox0 - 1;
  for (int idx = tid; idx < 3 * 33 * 33; idx += 256) {
    int c = idx / 1089;
    int rem = idx - c * 1089;
    int yy = rem / 33;
    int xx = rem - yy * 33;
    int iy = iy0 + yy, ix = ix0 + xx;
    float v = 0.f;
    if ((unsigned)iy < 256u && (unsigned)ix < 256u)
      v = img[((b * 3 + c) * 256 + iy) * 256 + ix];
    lds[(c * 33 + yy) * 34 + xx] = v;
  }
  __syncthreads();
  float acc[32];
#pragma unroll
  for (int oc = 0; oc < 32; ++oc) acc[oc] = 0.f;
  const float* wr = wT + r * 27 * 32;
#pragma unroll
  for (int c = 0; c < 3; ++c)
#pragma unroll
    for (int ky = 0; ky < 3; ++ky)
#pragma unroll
      for (int kx = 0; kx < 3; ++kx) {
        float iv = lds[(c * 33 + 2 * ty + ky) * 34 + 2 * tx + kx];
        const float* wk = wr + ((c * 3 + ky) * 3 + kx) * 32;
#pragma unroll
        for (int oc = 0; oc < 32; ++oc) acc[oc] = fmaf(iv, wk[oc], acc[oc]);
      }
  const int oy = oy0 + ty, ox = ox0 + tx;
  const float* br = bias + r * 32;
#pragma unroll
  for (int oc = 0; oc < 32; ++oc) {
    float v = acc[oc] + br[oc];
    h1[((bl * 32 + oc) * 128 + oy) * 128 + ox] = v > 0.f ? v : 0.f;
  }
}

// conv2: 32->64ch, 128->64. blockIdx.x = tilex(4) | occhunk(2)<<2,
// blockIdx.y = tiley(4), blockIdx.z = chunk-local sample. acc[32]/thread.
__global__ __launch_bounds__(256, 4) void conv2_k(
    const float* __restrict__ h1, const float* __restrict__ wT,
    const float* __restrict__ bias, const int* __restrict__ rgn,
    float* __restrict__ h2, int b0) {
  const int bl = blockIdx.z;
  const int b = b0 + bl;
  const int r = __builtin_amdgcn_readfirstlane(rgn[b]);
  const int oc0 = (blockIdx.x >> 2) * 32;
  const int oy0 = blockIdx.y * 16, ox0 = (blockIdx.x & 3) * 16;
  const int tid = threadIdx.x;
  const int ty = tid >> 4, tx = tid & 15;
  __shared__ float lds[4 * 33 * 34];  // 4 ic planes, 18 KB
  const int iy0 = 2 * oy0 - 1, ix0 = 2 * ox0 - 1;
  float acc[32];
#pragma unroll
  for (int oc = 0; oc < 32; ++oc) acc[oc] = 0.f;
  const float* wr = wT + r * 288 * 64 + oc0;
  const float* sb = h1 + (size_t)bl * 32 * 128 * 128;
  for (int icb = 0; icb < 32; icb += 4) {
    __syncthreads();
    for (int idx = tid; idx < 4 * 33 * 33; idx += 256) {
      int icl = idx / 1089;
      int rem = idx - icl * 1089;
      int yy = rem / 33, xx = rem - yy * 33;
      int iy = iy0 + yy, ix = ix0 + xx;
      float v = 0.f;
      if ((unsigned)iy < 128u && (unsigned)ix < 128u)
        v = sb[(size_t)(icb + icl) * 128 * 128 + iy * 128 + ix];
      lds[icl * 1122 + yy * 34 + xx] = v;
    }
    __syncthreads();
#pragma unroll
    for (int icl = 0; icl < 4; ++icl)
#pragma unroll
      for (int ky = 0; ky < 3; ++ky)
#pragma unroll
        for (int kx = 0; kx < 3; ++kx) {
          float iv = lds[icl * 1122 + (2 * ty + ky) * 34 + 2 * tx + kx];
          const float* wk = wr + (((icb + icl) * 9 + ky * 3 + kx) * 64);
#pragma unroll
          for (int oc = 0; oc < 32; ++oc) acc[oc] = fmaf(iv, wk[oc], acc[oc]);
        }
  }
  const int oy = oy0 + ty, ox = ox0 + tx;
  const float* br = bias + r * 64 + oc0;
#pragma unroll
  for (int oc = 0; oc < 32; ++oc) {
    float v = acc[oc] + br[oc];
    h2[((bl * 64 + oc0 + oc) * 64 + oy) * 64 + ox] = v > 0.f ? v : 0.f;
  }
}

// conv3: 64->128ch, 64->32, fused bias/ReLU/GAP. blockIdx.x = tile(4),
// blockIdx.y = occhunk(4), blockIdx.z = chunk-local sample. acc[32]/thread.
__global__ __launch_bounds__(256, 4) void conv3_k(
    const float* __restrict__ h2, const float* __restrict__ wT,
    const float* __restrict__ bias, const int* __restrict__ rgn,
    float* __restrict__ feat, int b0) {
  const int bl = blockIdx.z;
  const int b = b0 + bl;
  const int r = __builtin_amdgcn_readfirstlane(rgn[b]);
  const int tile = blockIdx.x;      // 2x2 tiles of 16x16 over 32x32
  const int oc0 = blockIdx.y * 32;  // 0..96
  const int oy0 = (tile >> 1) * 16, ox0 = (tile & 1) * 16;
  const int tid = threadIdx.x;
  const int ty = tid >> 4, tx = tid & 15;
  __shared__ float lds[4 * 33 * 34];
  const int iy0 = 2 * oy0 - 1, ix0 = 2 * ox0 - 1;
  float acc[32];
#pragma unroll
  for (int oc = 0; oc < 32; ++oc) acc[oc] = 0.f;
  const float* wr = wT + r * 576 * 128 + oc0;
  const float* sb = h2 + (size_t)bl * 64 * 64 * 64;
  for (int icb = 0; icb < 64; icb += 4) {
    __syncthreads();
    for (int idx = tid; idx < 4 * 33 * 33; idx += 256) {
      int icl = idx / 1089;
      int rem = idx - icl * 1089;
      int yy = rem / 33, xx = rem - yy * 33;
      int iy = iy0 + yy, ix = ix0 + xx;
      float v = 0.f;
      if ((unsigned)iy < 64u && (unsigned)ix < 64u)
        v = sb[(size_t)(icb + icl) * 64 * 64 + iy * 64 + ix];
      lds[icl * 1122 + yy * 34 + xx] = v;
    }
    __syncthreads();
#pragma unroll
    for (int icl = 0; icl < 4; ++icl)
#pragma unroll
      for (int ky = 0; ky < 3; ++ky)
#pragma unroll
        for (int kx = 0; kx < 3; ++kx) {
          float iv = lds[icl * 1122 + (2 * ty + ky) * 34 + 2 * tx + kx];
          const float* wk = wr + (((icb + icl) * 9 + ky * 3 + kx) * 128);
#pragma unroll
          for (int oc = 0; oc < 32; ++oc) acc[oc] = fmaf(iv, wk[oc], acc[oc]);
        }
  }
  // bias + ReLU + partial global-average-pool reduce
  __syncthreads();
  const float* br = bias + r * 128 + oc0;
  const int wave = tid >> 6, lane = tid & 63;
#pragma unroll
  for (int oc = 0; oc < 32; ++oc) {
    float v = acc[oc] + br[oc];
    v = v > 0.f ? v : 0.f;
#pragma unroll
    for (int off = 32; off > 0; off >>= 1) v += __shfl_down(v, off, 64);
    if (lane == 0) lds[oc * 4 + wave] = v;
  }
  __syncthreads();
  if (tid < 32) {
    float s = lds[tid * 4] + lds[tid * 4 + 1] + lds[tid * 4 + 2] + lds[tid * 4 + 3];
    atomicAdd(&feat[b * 128 + oc0 + tid], s);
  }
}

__global__ __launch_bounds__(256) void head_k(
    const float* __restrict__ feat, const float* __restrict__ fw,
    const float* __restrict__ fb, const int* __restrict__ rgn,
    float* __restrict__ out) {
  int t = threadIdx.x;  // 256 = 128 samples x 2 classes
  int b = t >> 1, c = t & 1;
  int r = rgn[b];
  const float* fwr = fw + (r * 2 + c) * 128;
  const float* fv = feat + b * 128;
  float a = 0.f;
#pragma unroll 8
  for (int j = 0; j < 128; ++j) a = fmaf(fwr[j], fv[j], a);
  out[t] = a * (1.0f / 1024.0f) + fb[r * 2 + c];
}

extern "C" void kernel_launch(void* const* d_in, const int* in_sizes, int n_in,
                              void* d_out, int out_size, void* d_ws, size_t ws_size,
                              hipStream_t stream) {
  const float* img = (const float*)d_in[0];
  const int* rgn_raw = (const int*)d_in[1];
  const float* w1 = (const float*)d_in[2];
  const float* b1 = (const float*)d_in[3];
  const float* w2 = (const float*)d_in[4];
  const float* b2 = (const float*)d_in[5];
  const float* w3 = (const float*)d_in[6];
  const float* b3 = (const float*)d_in[7];
  const float* fw = (const float*)d_in[8];
  const float* fb = (const float*)d_in[9];
  float* out = (float*)d_out;

  // --- workspace budget: chunk the batch so scratch fits ws_size ----------
  const size_t h1s = (size_t)32 * 128 * 128 * 4;  // 2 MB per sample
  const size_t h2s = (size_t)64 * 64 * 64 * 4;    // 1 MB per sample
  const size_t fixed = ((size_t)8 * 27 * 32 + (size_t)8 * 288 * 64 +
                        (size_t)8 * 576 * 128 + 128 * 128 + 128) * 4 +
                       16 * 256;  // tables + feat + rgn + alignment slop
  int C = 128;  // batch chunk (power of two, divides 128)
  while (C > 1 && fixed + (size_t)C * (h1s + h2s) > ws_size) C >>= 1;

  char* ws = (char*)d_ws;
  size_t off = 0;
  auto alloc = [&](size_t bytes) {
    char* p = ws + off;
    off += (bytes + 255) & ~(size_t)255;
    return p;
  };
  float* h1 = (float*)alloc((size_t)C * h1s);
  float* h2 = (float*)alloc((size_t)C * h2s);
  float* wT1 = (float*)alloc((size_t)8 * 27 * 32 * 4);
  float* wT2 = (float*)alloc((size_t)8 * 288 * 64 * 4);
  float* wT3 = (float*)alloc((size_t)8 * 576 * 128 * 4);
  float* feat = (float*)alloc((size_t)128 * 128 * 4);
  int* rgn = (int*)alloc((size_t)128 * 4);

  hipLaunchKernelGGL(prep_k, dim3(1), dim3(128), 0, stream, rgn_raw, rgn, feat);
  hipLaunchKernelGGL(repack_k, dim3((8 * 32 * 27 + 255) / 256), dim3(256), 0, stream,
                     w1, wT1, 32, 27, 8 * 32 * 27);
  hipLaunchKernelGGL(repack_k, dim3((8 * 64 * 288 + 255) / 256), dim3(256), 0, stream,
                     w2, wT2, 64, 288, 8 * 64 * 288);
  hipLaunchKernelGGL(repack_k, dim3((8 * 128 * 576 + 255) / 256), dim3(256), 0, stream,
                     w3, wT3, 128, 576, 8 * 128 * 576);

  for (int b0 = 0; b0 < 128; b0 += C) {
    hipLaunchKernelGGL(conv1_k, dim3(8, 8, C), dim3(256), 0, stream, img, wT1, b1, rgn, h1, b0);
    hipLaunchKernelGGL(conv2_k, dim3(8, 4, C), dim3(256), 0, stream, h1, wT2, b2, rgn, h2, b0);
    hipLaunchKernelGGL(conv3_k, dim3(4, 4, C), dim3(256), 0, stream, h2, wT3, b3, rgn, feat, b0);
  }
  hipLaunchKernelGGL(head_k, dim3(1), dim3(256), 0, stream, feat, fw, fb, rgn, out);
}

// Round 5
// 563.062 us; speedup vs baseline: 2.5558x; 2.1250x over previous
//
#include <hip/hip_runtime.h>
#include <cstdint>

// ---------------------------------------------------------------------------
// RegionModel R5: bf16 MFMA implicit-GEMM for all three convs.
//   conv1: 3->32,  256->128 (K=27 pad 32), conv2: 32->64, 128->64 (K=288),
//   conv3: 64->128, 64->32 (K=576) fused bias+ReLU+GAP.
// A = weights (M=oc) pre-packed to exact frag layout; B = activations gathered
// per-lane from zero-halo-padded bf16 buffers (LDS dOff table, no bounds
// checks). mfma_f32_16x16x32_bf16; fp32 accumulate. GAP via shfl_xor(w=16)
// + atomicAdd. Head fp32. ws-adaptive batch chunking (R1/R3 overran d_ws).
// fp32 vector ceiling was ~270us (no fp32 MFMA); R4 measured 1196us with
// AGPR-offloaded accs (VGPR_Count=32). MFMA floor ~21us, HBM floor ~80us.
// ---------------------------------------------------------------------------

typedef __attribute__((ext_vector_type(8))) short short8;
typedef __attribute__((ext_vector_type(4))) float floatx4;

__device__ inline unsigned short f2bf(float f) {
  union { float f; unsigned u; } x;
  x.f = f;
  unsigned u = x.u;
  u += 0x7FFFu + ((u >> 16) & 1u);  // round-to-nearest-even
  return (unsigned short)(u >> 16);
}

__global__ __launch_bounds__(128) void prep_k(const int* __restrict__ rp,
                                              int* __restrict__ rout,
                                              float* __restrict__ feat) {
  // Defensive: region may be stored int64 (values 0..7 -> odd int32 words 0).
  __shared__ int is64;
  if (threadIdx.x == 0) {
    int odd_or = 0;
    for (int i = 0; i < 64; ++i) odd_or |= rp[2 * i + 1];
    is64 = (odd_or == 0) ? 1 : 0;
  }
  __syncthreads();
  int b = threadIdx.x;
  int r = is64 ? rp[2 * b] : rp[b];
  rout[b] = r & 7;
  float* fr = feat + b * 128;
  for (int j = 0; j < 128; ++j) fr[j] = 0.f;
}

// Pack weights [R][OC][IC][3][3] fp32 -> frag layout [r][kg][mt][lane][j] bf16.
// oc = mt*16 + (lane&15), k = kg*32 + ((lane>>4)&3)*8 + j; k >= IC*9 -> 0.
__global__ __launch_bounds__(256) void pack_k(const float* __restrict__ w,
                                              unsigned short* __restrict__ dst,
                                              int OC, int IC, int KG, int MT,
                                              int total) {
  int t = blockIdx.x * blockDim.x + threadIdx.x;
  if (t >= total) return;
  int j = t & 7;
  int l = (t >> 3) & 63;
  int u = t >> 9;
  int mt = u % MT;
  u /= MT;
  int kg = u % KG;
  int r = u / KG;
  int oc = mt * 16 + (l & 15);
  int k = kg * 32 + ((l >> 4) & 3) * 8 + j;
  float val = 0.f;
  if (k < IC * 9) {
    int ic = k / 9, tap = k % 9;
    val = w[((r * OC + oc) * IC + ic) * 9 + tap];
  }
  dst[t] = f2bf(val);
}

// Convert fp32 image chunk to zero-halo-padded bf16 [C][3][258][258].
__global__ __launch_bounds__(256) void imgcvt_k(const float* __restrict__ img,
                                                unsigned short* __restrict__ dst,
                                                int b0, int total) {
  int t = blockIdx.x * blockDim.x + threadIdx.x;
  if (t >= total) return;
  int plane = t / (258 * 258);
  int rem = t - plane * (258 * 258);
  int y = rem / 258, x = rem - y * 258;
  unsigned short v = 0;
  if (y >= 1 && y <= 256 && x >= 1 && x <= 256)
    v = f2bf(img[((size_t)(b0 * 3 + plane)) * 65536 + (y - 1) * 256 + (x - 1)]);
  dst[t] = v;
}

// Zero the halo of a padded bf16 activation buffer [planes][HP][WP].
__global__ __launch_bounds__(256) void halo_k(unsigned short* __restrict__ buf,
                                              int planes, int HP, int WP) {
  int per = 2 * WP + 2 * (HP - 2);
  int t = blockIdx.x * blockDim.x + threadIdx.x;
  if (t >= planes * per) return;
  int p = t / per, i = t - p * per;
  unsigned short* pb = buf + (size_t)p * HP * WP;
  int idx;
  if (i < WP) idx = i;
  else if (i < 2 * WP) idx = (HP - 1) * WP + (i - WP);
  else {
    int ii = i - 2 * WP;
    int row = 1 + (ii >> 1);
    idx = row * WP + ((ii & 1) ? (WP - 1) : 0);
  }
  pb[idx] = 0;
}

// MFMA implicit-GEMM conv, stride 2, pad 1 (via zero halo). Block = 256 thr
// = 4 waves x 16 pixels; wave covers all OC (MT m-tiles of 16).
// A (weights) frag: lane&15 = oc%16, k = kg*32+((lane>>4)&3)*8+j (pre-packed).
// B (activations) frag: lane&15 = pixel, same k mapping, gathered via LDS
// offset table from padded input. D: oc_row = (lane>>4)*4+reg, px = lane&15.
template <int IC, int OC, int OW, int IHP, int IWP, int KG, int MT, int OPH,
          int OPW, bool GAP>
__global__ __launch_bounds__(256, 4) void convm_k(
    const unsigned short* __restrict__ in, const unsigned short* __restrict__ wp,
    const float* __restrict__ bias, const int* __restrict__ rgn,
    unsigned short* __restrict__ outp, float* __restrict__ feat, int b0) {
  const int tid = threadIdx.x;
  const int bl = blockIdx.y;
  const int b = b0 + bl;
  const int r = __builtin_amdgcn_readfirstlane(rgn[b]);
  __shared__ int sOff[KG * 32];
  __shared__ float sBias[OC];
  for (int t = tid; t < KG * 32; t += 256) {
    int kk = (t < IC * 9) ? t : 0;  // zero-weight pad slots -> safe offset 0
    int ic = kk / 9, tap = kk % 9;
    sOff[t] = (ic * IHP + tap / 3) * IWP + (tap % 3);
  }
  for (int t = tid; t < OC; t += 256) sBias[t] = bias[r * OC + t];
  __syncthreads();

  const int lane = tid & 63;
  const int n = tid & 15;
  const int q = (tid >> 4) & 3;
  const int px = blockIdx.x * 64 + (tid >> 6) * 16 + n;
  const int oy = px / OW, ox = px % OW;
  const unsigned pixoff = (unsigned)(2 * oy * IWP + 2 * ox);
  const unsigned short* inb = in + (size_t)bl * IC * IHP * IWP;
  const short8* wpb = (const short8*)wp + (size_t)r * KG * MT * 64 + lane;

  floatx4 acc[MT];
#pragma unroll
  for (int m = 0; m < MT; ++m) acc[m] = (floatx4){0.f, 0.f, 0.f, 0.f};

  for (int kg = 0; kg < KG; ++kg) {
    short8 a[MT];
#pragma unroll
    for (int m = 0; m < MT; ++m) a[m] = wpb[(kg * MT + m) * 64];
    union {
      unsigned short u[8];
      short8 v;
    } bf;
    const int kb = kg * 32 + q * 8;
#pragma unroll
    for (int j = 0; j < 8; ++j) bf.u[j] = inb[pixoff + (unsigned)sOff[kb + j]];
#pragma unroll
    for (int m = 0; m < MT; ++m)
      acc[m] = __builtin_amdgcn_mfma_f32_16x16x32_bf16(a[m], bf.v, acc[m], 0, 0, 0);
  }

  if constexpr (!GAP) {
    unsigned short* ob = outp + (size_t)bl * OC * OPH * OPW;
#pragma unroll
    for (int m = 0; m < MT; ++m)
#pragma unroll
      for (int rr = 0; rr < 4; ++rr) {
        int oc = m * 16 + q * 4 + rr;
        float v = acc[m][rr] + sBias[oc];
        v = v > 0.f ? v : 0.f;
        ob[((size_t)oc * OPH + oy + 1) * OPW + ox + 1] = f2bf(v);
      }
  } else {
#pragma unroll
    for (int m = 0; m < MT; ++m)
#pragma unroll
      for (int rr = 0; rr < 4; ++rr) {
        int oc = m * 16 + q * 4 + rr;
        float v = acc[m][rr] + sBias[oc];
        v = v > 0.f ? v : 0.f;
        v += __shfl_xor(v, 1, 16);
        v += __shfl_xor(v, 2, 16);
        v += __shfl_xor(v, 4, 16);
        v += __shfl_xor(v, 8, 16);
        if (n == 0) atomicAdd(&feat[b * 128 + oc], v);
      }
  }
}

__global__ __launch_bounds__(256) void head_k(
    const float* __restrict__ feat, const float* __restrict__ fw,
    const float* __restrict__ fb, const int* __restrict__ rgn,
    float* __restrict__ out) {
  int t = threadIdx.x;  // 256 = 128 samples x 2 classes
  int b = t >> 1, c = t & 1;
  int r = rgn[b];
  const float* fwr = fw + (r * 2 + c) * 128;
  const float* fv = feat + b * 128;
  float a = 0.f;
#pragma unroll 8
  for (int j = 0; j < 128; ++j) a = fmaf(fwr[j], fv[j], a);
  out[t] = a * (1.0f / 1024.0f) + fb[r * 2 + c];
}

extern "C" void kernel_launch(void* const* d_in, const int* in_sizes, int n_in,
                              void* d_out, int out_size, void* d_ws, size_t ws_size,
                              hipStream_t stream) {
  const float* img = (const float*)d_in[0];
  const int* rgn_raw = (const int*)d_in[1];
  const float* w1 = (const float*)d_in[2];
  const float* b1 = (const float*)d_in[3];
  const float* w2 = (const float*)d_in[4];
  const float* b2 = (const float*)d_in[5];
  const float* w3 = (const float*)d_in[6];
  const float* b3 = (const float*)d_in[7];
  const float* fw = (const float*)d_in[8];
  const float* fb = (const float*)d_in[9];
  float* out = (float*)d_out;

  // Per-sample padded bf16 scratch
  const size_t imgp_s = (size_t)3 * 258 * 258 * 2;   // 399 KB
  const size_t h1p_s = (size_t)32 * 130 * 130 * 2;   // 1.08 MB
  const size_t h2p_s = (size_t)64 * 66 * 66 * 2;     // 557 KB
  const size_t per_sample = imgp_s + h1p_s + h2p_s;  // ~1.94 MB
  const size_t fixed = (size_t)8192 * 2 + (size_t)147456 * 2 +
                       (size_t)589824 * 2 + 128 * 128 * 4 + 512 + 16 * 256;
  int C = 128;  // batch chunk (power of two)
  while (C > 1 && fixed + (size_t)C * per_sample > ws_size) C >>= 1;

  char* ws = (char*)d_ws;
  size_t off = 0;
  auto alloc = [&](size_t bytes) {
    char* p = ws + off;
    off += (bytes + 255) & ~(size_t)255;
    return p;
  };
  unsigned short* imgp = (unsigned short*)alloc((size_t)C * imgp_s);
  unsigned short* h1p = (unsigned short*)alloc((size_t)C * h1p_s);
  unsigned short* h2p = (unsigned short*)alloc((size_t)C * h2p_s);
  unsigned short* w1p = (unsigned short*)alloc((size_t)8192 * 2);
  unsigned short* w2p = (unsigned short*)alloc((size_t)147456 * 2);
  unsigned short* w3p = (unsigned short*)alloc((size_t)589824 * 2);
  float* feat = (float*)alloc((size_t)128 * 128 * 4);
  int* rgn = (int*)alloc((size_t)128 * 4);

  hipLaunchKernelGGL(prep_k, dim3(1), dim3(128), 0, stream, rgn_raw, rgn, feat);
  hipLaunchKernelGGL(pack_k, dim3((8192 + 255) / 256), dim3(256), 0, stream,
                     w1, w1p, 32, 3, 1, 2, 8192);
  hipLaunchKernelGGL(pack_k, dim3((147456 + 255) / 256), dim3(256), 0, stream,
                     w2, w2p, 64, 32, 9, 4, 147456);
  hipLaunchKernelGGL(pack_k, dim3((589824 + 255) / 256), dim3(256), 0, stream,
                     w3, w3p, 128, 64, 18, 8, 589824);
  {  // zero halos once; interiors are rewritten every chunk
    int n1 = C * 32 * (2 * 130 + 2 * 128);
    hipLaunchKernelGGL(halo_k, dim3((n1 + 255) / 256), dim3(256), 0, stream,
                       h1p, C * 32, 130, 130);
    int n2 = C * 64 * (2 * 66 + 2 * 64);
    hipLaunchKernelGGL(halo_k, dim3((n2 + 255) / 256), dim3(256), 0, stream,
                       h2p, C * 64, 66, 66);
  }

  for (int b0 = 0; b0 < 128; b0 += C) {
    int totimg = C * 3 * 258 * 258;
    hipLaunchKernelGGL(imgcvt_k, dim3((totimg + 255) / 256), dim3(256), 0, stream,
                       img, imgp, b0, totimg);
    hipLaunchKernelGGL((convm_k<3, 32, 128, 258, 258, 1, 2, 130, 130, false>),
                       dim3(256, C), dim3(256), 0, stream,
                       imgp, w1p, b1, rgn, h1p, feat, b0);
    hipLaunchKernelGGL((convm_k<32, 64, 64, 130, 130, 9, 4, 66, 66, false>),
                       dim3(64, C), dim3(256), 0, stream,
                       h1p, w2p, b2, rgn, h2p, feat, b0);
    hipLaunchKernelGGL((convm_k<64, 128, 32, 66, 66, 18, 8, 1, 1, true>),
                       dim3(16, C), dim3(256), 0, stream,
                       h2p, w3p, b3, rgn, (unsigned short*)nullptr, feat, b0);
  }
  hipLaunchKernelGGL(head_k, dim3(1), dim3(256), 0, stream, feat, fw, fb, rgn, out);
}

// Round 6
// 425.294 us; speedup vs baseline: 3.3837x; 1.3239x over previous
//
#include <hip/hip_runtime.h>
#include <cstdint>

// ---------------------------------------------------------------------------
// RegionModel R6: bf16 MFMA implicit-GEMM, CHANNELS-LAST activations.
// R5 was latency-bound (MfmaUtil 5%, VALUBusy 17%, HBM 17%): per-lane im2col
// was 8 scalar ushort loads / kg. R6 stores activations [y][x][C] (zero halo)
// and splits conv into 9 per-tap GEMMs with K=IC, so each lane's B-fragment
// is 8 CONTIGUOUS ushorts -> one dwordx4. Tap offsets are compile-time.
// conv1 uses row-padded K (3 rows x 16: kx0..3 x c0..3, zero-padded weights).
// Weights pre-packed per-tap to exact A-frag layout. conv3 fuses
// bias+ReLU+GAP (shfl_xor w=16 + atomicAdd). ws-adaptive chunking retained.
// ---------------------------------------------------------------------------

typedef __attribute__((ext_vector_type(8))) short short8;
typedef __attribute__((ext_vector_type(4))) float floatx4;
typedef __attribute__((ext_vector_type(4))) unsigned short ushort4v;
typedef __attribute__((ext_vector_type(2))) unsigned int uint2v;

__device__ inline unsigned short f2bf(float f) {
  union { float f; unsigned u; } x;
  x.f = f;
  unsigned u = x.u;
  u += 0x7FFFu + ((u >> 16) & 1u);  // round-to-nearest-even
  return (unsigned short)(u >> 16);
}

__global__ __launch_bounds__(128) void prep_k(const int* __restrict__ rp,
                                              int* __restrict__ rout,
                                              float* __restrict__ feat) {
  __shared__ int is64;
  if (threadIdx.x == 0) {
    int odd_or = 0;
    for (int i = 0; i < 64; ++i) odd_or |= rp[2 * i + 1];
    is64 = (odd_or == 0) ? 1 : 0;
  }
  __syncthreads();
  int b = threadIdx.x;
  int r = is64 ? rp[2 * b] : rp[b];
  rout[b] = r & 7;
  float* fr = feat + b * 128;
  for (int j = 0; j < 128; ++j) fr[j] = 0.f;
}

// conv1 weights -> [r][kg(2)][mt(2)][lane][j] ; k = kg*32+q*8+j maps to
// row = kg*2+(q>>1), idx=(q&1)*8+j, kx=idx>>2, c=idx&3; pad slots -> 0.
__global__ __launch_bounds__(256) void pack1_k(const float* __restrict__ w,
                                               unsigned short* __restrict__ dst) {
  int t = blockIdx.x * blockDim.x + threadIdx.x;
  if (t >= 16384) return;
  int j = t & 7, lane = (t >> 3) & 63, mt = (t >> 9) & 1, kg = (t >> 10) & 1,
      r = t >> 11;
  int oc = mt * 16 + (lane & 15);
  int q = (lane >> 4) & 3;
  int row = kg * 2 + (q >> 1);
  int idx = (q & 1) * 8 + j;
  int kx = idx >> 2, c = idx & 3;
  float val = 0.f;
  if (row < 3 && kx < 3 && c < 3) val = w[((r * 32 + oc) * 3 + c) * 9 + row * 3 + kx];
  dst[t] = f2bf(val);
}

// conv2/3 weights [R][OC][IC][3][3] -> [r][tap][s][mt][lane][j], ic=s*32+q*8+j
template <int OC, int IC, int SUBK, int MT>
__global__ __launch_bounds__(256) void packT_k(const float* __restrict__ w,
                                               unsigned short* __restrict__ dst) {
  const int total = 8 * 9 * SUBK * MT * 512;
  int t = blockIdx.x * blockDim.x + threadIdx.x;
  if (t >= total) return;
  int j = t & 7, lane = (t >> 3) & 63;
  int u = t >> 9;
  int mt = u % MT; u /= MT;
  int s = u % SUBK; u /= SUBK;
  int tap = u % 9;
  int r = u / 9;
  int oc = mt * 16 + (lane & 15);
  int ic = s * 32 + ((lane >> 4) & 3) * 8 + j;
  dst[t] = f2bf(w[((r * OC + oc) * IC + ic) * 9 + tap]);
}

// fp32 planar image chunk -> padded channels-last bf16 [s][258][258][4]
__global__ __launch_bounds__(256) void imgcvt_k(const float* __restrict__ img,
                                                unsigned short* __restrict__ dst,
                                                int b0, int total) {
  int t = blockIdx.x * blockDim.x + threadIdx.x;
  if (t >= total) return;
  int s = t / (258 * 258);
  int rem = t - s * (258 * 258);
  int y = rem / 258, x = rem - y * 258;
  ushort4v v = {0, 0, 0, 0};
  if (y >= 1 && y <= 256 && x >= 1 && x <= 256) {
    const float* ip = img + ((size_t)(b0 + s) * 3) * 65536 + (y - 1) * 256 + (x - 1);
    v.x = f2bf(ip[0]);
    v.y = f2bf(ip[65536]);
    v.z = f2bf(ip[2 * 65536]);
  }
  *(ushort4v*)(dst + (size_t)t * 4) = v;
}

// zero halo of channels-last buffer [nsamp][HP][WP][IC]
template <int IC>
__global__ __launch_bounds__(256) void haloc_k(unsigned short* __restrict__ buf,
                                               int nsamp, int HP, int WP) {
  int per = 2 * WP + 2 * (HP - 2);
  int t = blockIdx.x * blockDim.x + threadIdx.x;
  if (t >= nsamp * per) return;
  int s = t / per, i = t - s * per;
  int y, x;
  if (i < WP) { y = 0; x = i; }
  else if (i < 2 * WP) { y = HP - 1; x = i - WP; }
  else {
    int ii = i - 2 * WP;
    y = 1 + (ii >> 1);
    x = (ii & 1) ? (WP - 1) : 0;
  }
  unsigned short* p = buf + ((size_t)s * HP * WP + y * WP + x) * IC;
  short8 z = {0, 0, 0, 0, 0, 0, 0, 0};
#pragma unroll
  for (int j = 0; j < IC / 8; ++j) ((short8*)p)[j] = z;
}

// conv1: 3->32, 256->128. imgp [258][258][4] c-last, K = 3 rows x 16.
__global__ __launch_bounds__(256, 4) void conv1_k(
    const unsigned short* __restrict__ in, const unsigned short* __restrict__ wp,
    const float* __restrict__ bias, const int* __restrict__ rgn,
    unsigned short* __restrict__ outp, int b0) {
  const int tid = threadIdx.x;
  const int bl = blockIdx.y;
  const int r = __builtin_amdgcn_readfirstlane(rgn[b0 + bl]);
  __shared__ float sBias[32];
  if (tid < 32) sBias[tid] = bias[r * 32 + tid];
  __syncthreads();
  const int lane = tid & 63, n = tid & 15, q = (tid >> 4) & 3;
  const int px = blockIdx.x * 64 + (tid >> 6) * 16 + n;
  const int oy = px >> 7, ox = px & 127;
  const unsigned short* inb = in + (size_t)bl * 258 * 258 * 4;
  const short8* wpb = (const short8*)wp + (size_t)r * 256 + lane;
  floatx4 acc[2];
  acc[0] = (floatx4){0.f, 0.f, 0.f, 0.f};
  acc[1] = acc[0];
#pragma unroll
  for (int kg = 0; kg < 2; ++kg) {
    int row = kg * 2 + (q >> 1);
    int rowc = (row < 3) ? row : 0;  // pad rows: zero weights, safe addr
    const uint2v* p =
        (const uint2v*)(inb + ((size_t)(2 * oy + rowc) * 258 + 2 * ox) * 4 +
                        (q & 1) * 8);
    union { uint2v u[2]; short8 v; } bf;
    bf.u[0] = p[0];
    bf.u[1] = p[1];
#pragma unroll
    for (int m = 0; m < 2; ++m) {
      short8 a = wpb[(kg * 2 + m) * 64];
      acc[m] = __builtin_amdgcn_mfma_f32_16x16x32_bf16(a, bf.v, acc[m], 0, 0, 0);
    }
  }
  unsigned short* ob = outp + (size_t)bl * 130 * 130 * 32;
#pragma unroll
  for (int m = 0; m < 2; ++m) {
    ushort4v st;
#pragma unroll
    for (int rr = 0; rr < 4; ++rr) {
      float v = acc[m][rr] + sBias[m * 16 + q * 4 + rr];
      st[rr] = f2bf(v > 0.f ? v : 0.f);
    }
    *(ushort4v*)(ob + ((size_t)(oy + 1) * 130 + ox + 1) * 32 + m * 16 + q * 4) = st;
  }
}

// per-tap MFMA conv, stride 2, channels-last in/out, zero halo.
template <int IC, int OC, int OW, int IWP, int SUBK, int MT, int OPW, bool GAP>
__global__ __launch_bounds__(256, 4) void convm_k(
    const unsigned short* __restrict__ in, const unsigned short* __restrict__ wp,
    const float* __restrict__ bias, const int* __restrict__ rgn,
    unsigned short* __restrict__ outp, float* __restrict__ feat, int b0) {
  const int tid = threadIdx.x;
  const int bl = blockIdx.y;
  const int b = b0 + bl;
  const int r = __builtin_amdgcn_readfirstlane(rgn[b]);
  __shared__ float sBias[OC];
  for (int t = tid; t < OC; t += 256) sBias[t] = bias[r * OC + t];
  __syncthreads();
  const int lane = tid & 63, n = tid & 15, q = (tid >> 4) & 3;
  const int px = blockIdx.x * 64 + (tid >> 6) * 16 + n;
  const int oy = px / OW, ox = px % OW;
  const unsigned short* inb =
      in + (size_t)bl * IC * IWP * IWP + (size_t)(2 * oy * IWP + 2 * ox) * IC + q * 8;
  const short8* wpb = (const short8*)wp + (size_t)r * 9 * SUBK * MT * 64 + lane;
  floatx4 acc[MT];
#pragma unroll
  for (int m = 0; m < MT; ++m) acc[m] = (floatx4){0.f, 0.f, 0.f, 0.f};
#pragma unroll
  for (int tap = 0; tap < 9; ++tap) {
    const int ky = tap / 3, kx = tap % 3;
#pragma unroll
    for (int s = 0; s < SUBK; ++s) {
      short8 bf = *(const short8*)(inb + (size_t)(ky * IWP + kx) * IC + s * 32);
#pragma unroll
      for (int m = 0; m < MT; ++m) {
        short8 a = wpb[((tap * SUBK + s) * MT + m) * 64];
        acc[m] = __builtin_amdgcn_mfma_f32_16x16x32_bf16(a, bf, acc[m], 0, 0, 0);
      }
    }
  }
  if constexpr (!GAP) {
    unsigned short* ob = outp + (size_t)bl * OC * OPW * OPW;
#pragma unroll
    for (int m = 0; m < MT; ++m) {
      ushort4v st;
#pragma unroll
      for (int rr = 0; rr < 4; ++rr) {
        float v = acc[m][rr] + sBias[m * 16 + q * 4 + rr];
        st[rr] = f2bf(v > 0.f ? v : 0.f);
      }
      *(ushort4v*)(ob + ((size_t)(oy + 1) * OPW + ox + 1) * OC + m * 16 + q * 4) = st;
    }
  } else {
#pragma unroll
    for (int m = 0; m < MT; ++m)
#pragma unroll
      for (int rr = 0; rr < 4; ++rr) {
        int oc = m * 16 + q * 4 + rr;
        float v = acc[m][rr] + sBias[oc];
        v = v > 0.f ? v : 0.f;
        v += __shfl_xor(v, 1, 16);
        v += __shfl_xor(v, 2, 16);
        v += __shfl_xor(v, 4, 16);
        v += __shfl_xor(v, 8, 16);
        if (n == 0) atomicAdd(&feat[b * 128 + oc], v);
      }
  }
}

__global__ __launch_bounds__(256) void head_k(
    const float* __restrict__ feat, const float* __restrict__ fw,
    const float* __restrict__ fb, const int* __restrict__ rgn,
    float* __restrict__ out) {
  int t = threadIdx.x;  // 128 samples x 2 classes
  int b = t >> 1, c = t & 1;
  int r = rgn[b];
  const float* fwr = fw + (r * 2 + c) * 128;
  const float* fv = feat + b * 128;
  float a = 0.f;
#pragma unroll 8
  for (int j = 0; j < 128; ++j) a = fmaf(fwr[j], fv[j], a);
  out[t] = a * (1.0f / 1024.0f) + fb[r * 2 + c];
}

extern "C" void kernel_launch(void* const* d_in, const int* in_sizes, int n_in,
                              void* d_out, int out_size, void* d_ws, size_t ws_size,
                              hipStream_t stream) {
  const float* img = (const float*)d_in[0];
  const int* rgn_raw = (const int*)d_in[1];
  const float* w1 = (const float*)d_in[2];
  const float* b1 = (const float*)d_in[3];
  const float* w2 = (const float*)d_in[4];
  const float* b2 = (const float*)d_in[5];
  const float* w3 = (const float*)d_in[6];
  const float* b3 = (const float*)d_in[7];
  const float* fw = (const float*)d_in[8];
  const float* fb = (const float*)d_in[9];
  float* out = (float*)d_out;

  const size_t imgp_s = (size_t)258 * 258 * 4 * 2;   // 532 KB
  const size_t h1p_s = (size_t)130 * 130 * 32 * 2;   // 1.08 MB
  const size_t h2p_s = (size_t)66 * 66 * 64 * 2;     // 557 KB
  const size_t per_sample = imgp_s + h1p_s + h2p_s;  // ~2.17 MB
  const size_t fixed = (size_t)16384 * 2 + (size_t)147456 * 2 +
                       (size_t)589824 * 2 + 128 * 128 * 4 + 512 + 16 * 256;
  int C = 128;
  while (C > 1 && fixed + (size_t)C * per_sample > ws_size) C >>= 1;

  char* ws = (char*)d_ws;
  size_t off = 0;
  auto alloc = [&](size_t bytes) {
    char* p = ws + off;
    off += (bytes + 255) & ~(size_t)255;
    return p;
  };
  unsigned short* imgp = (unsigned short*)alloc((size_t)C * imgp_s);
  unsigned short* h1p = (unsigned short*)alloc((size_t)C * h1p_s);
  unsigned short* h2p = (unsigned short*)alloc((size_t)C * h2p_s);
  unsigned short* w1p = (unsigned short*)alloc((size_t)16384 * 2);
  unsigned short* w2p = (unsigned short*)alloc((size_t)147456 * 2);
  unsigned short* w3p = (unsigned short*)alloc((size_t)589824 * 2);
  float* feat = (float*)alloc((size_t)128 * 128 * 4);
  int* rgn = (int*)alloc((size_t)128 * 4);

  hipLaunchKernelGGL(prep_k, dim3(1), dim3(128), 0, stream, rgn_raw, rgn, feat);
  hipLaunchKernelGGL(pack1_k, dim3(64), dim3(256), 0, stream, w1, w1p);
  hipLaunchKernelGGL((packT_k<64, 32, 1, 4>), dim3(576), dim3(256), 0, stream, w2, w2p);
  hipLaunchKernelGGL((packT_k<128, 64, 2, 8>), dim3(2304), dim3(256), 0, stream, w3, w3p);
  {  // zero halos once; interiors rewritten every chunk
    int n1 = C * (2 * 130 + 2 * 128);
    hipLaunchKernelGGL((haloc_k<32>), dim3((n1 + 255) / 256), dim3(256), 0, stream,
                       h1p, C, 130, 130);
    int n2 = C * (2 * 66 + 2 * 64);
    hipLaunchKernelGGL((haloc_k<64>), dim3((n2 + 255) / 256), dim3(256), 0, stream,
                       h2p, C, 66, 66);
  }

  for (int b0 = 0; b0 < 128; b0 += C) {
    int totimg = C * 258 * 258;
    hipLaunchKernelGGL(imgcvt_k, dim3((totimg + 255) / 256), dim3(256), 0, stream,
                       img, imgp, b0, totimg);
    hipLaunchKernelGGL(conv1_k, dim3(256, C), dim3(256), 0, stream,
                       imgp, w1p, b1, rgn, h1p, b0);
    hipLaunchKernelGGL((convm_k<32, 64, 64, 130, 1, 4, 66, false>),
                       dim3(64, C), dim3(256), 0, stream,
                       h1p, w2p, b2, rgn, h2p, feat, b0);
    hipLaunchKernelGGL((convm_k<64, 128, 32, 66, 2, 8, 1, true>),
                       dim3(16, C), dim3(256), 0, stream,
                       h2p, w3p, b3, rgn, (unsigned short*)nullptr, feat, b0);
  }
  hipLaunchKernelGGL(head_k, dim3(1), dim3(256), 0, stream, feat, fw, fb, rgn, out);
}

// Round 7
// 381.491 us; speedup vs baseline: 3.7722x; 1.1148x over previous
//
#include <hip/hip_runtime.h>
#include <cstdint>

// ---------------------------------------------------------------------------
// RegionModel R7: bf16 MFMA implicit-GEMM, channels-last, 64 pixels/wave.
// R6 was latency-bound (MfmaUtil 7.6%, VALUBusy 8%, HBM 22%): 16 px/wave
// meant A-frags re-fetched per wave (conv2: 1.2 GB L2 = ~34 us) and only
// 4 MFMAs per B-load. R7: wave = 4 n-tiles x 16 px; per (tap,s): MT A-loads
// + 4 B-loads -> 4*MT MFMAs (conv2 2:1 compute:load), A-traffic /4.
// conv3 splits OC in halves across blocks (acc stays at 64 regs). GAP:
// bias+ReLU per pixel, nt-presum, shfl_xor(16) reduce, atomics /4.
// ---------------------------------------------------------------------------

typedef __attribute__((ext_vector_type(8))) short short8;
typedef __attribute__((ext_vector_type(4))) float floatx4;
typedef __attribute__((ext_vector_type(4))) unsigned short ushort4v;

__device__ inline unsigned short f2bf(float f) {
  union { float f; unsigned u; } x;
  x.f = f;
  unsigned u = x.u;
  u += 0x7FFFu + ((u >> 16) & 1u);  // round-to-nearest-even
  return (unsigned short)(u >> 16);
}

__global__ __launch_bounds__(128) void prep_k(const int* __restrict__ rp,
                                              int* __restrict__ rout,
                                              float* __restrict__ feat) {
  __shared__ int is64;
  if (threadIdx.x == 0) {
    int odd_or = 0;
    for (int i = 0; i < 64; ++i) odd_or |= rp[2 * i + 1];
    is64 = (odd_or == 0) ? 1 : 0;
  }
  __syncthreads();
  int b = threadIdx.x;
  int r = is64 ? rp[2 * b] : rp[b];
  rout[b] = r & 7;
  float* fr = feat + b * 128;
  for (int j = 0; j < 128; ++j) fr[j] = 0.f;
}

// conv1 weights -> [r][kg(2)][mt(2)][lane][j] ; k = kg*32+q*8+j maps to
// row = kg*2+(q>>1), idx=(q&1)*8+j, kx=idx>>2, c=idx&3; pad slots -> 0.
__global__ __launch_bounds__(256) void pack1_k(const float* __restrict__ w,
                                               unsigned short* __restrict__ dst) {
  int t = blockIdx.x * blockDim.x + threadIdx.x;
  if (t >= 16384) return;
  int j = t & 7, lane = (t >> 3) & 63, mt = (t >> 9) & 1, kg = (t >> 10) & 1,
      r = t >> 11;
  int oc = mt * 16 + (lane & 15);
  int q = (lane >> 4) & 3;
  int row = kg * 2 + (q >> 1);
  int idx = (q & 1) * 8 + j;
  int kx = idx >> 2, c = idx & 3;
  float val = 0.f;
  if (row < 3 && kx < 3 && c < 3) val = w[((r * 32 + oc) * 3 + c) * 9 + row * 3 + kx];
  dst[t] = f2bf(val);
}

// conv2/3 weights [R][OC][IC][3][3] -> [r][tap][s][mt][lane][j], ic=s*32+q*8+j
template <int OC, int IC, int SUBK, int MTG>
__global__ __launch_bounds__(256) void packT_k(const float* __restrict__ w,
                                               unsigned short* __restrict__ dst) {
  const int total = 8 * 9 * SUBK * MTG * 512;
  int t = blockIdx.x * blockDim.x + threadIdx.x;
  if (t >= total) return;
  int j = t & 7, lane = (t >> 3) & 63;
  int u = t >> 9;
  int mt = u % MTG; u /= MTG;
  int s = u % SUBK; u /= SUBK;
  int tap = u % 9;
  int r = u / 9;
  int oc = mt * 16 + (lane & 15);
  int ic = s * 32 + ((lane >> 4) & 3) * 8 + j;
  dst[t] = f2bf(w[((r * OC + oc) * IC + ic) * 9 + tap]);
}

// fp32 planar image chunk -> padded channels-last bf16 [s][258][258][4]
__global__ __launch_bounds__(256) void imgcvt_k(const float* __restrict__ img,
                                                unsigned short* __restrict__ dst,
                                                int b0, int total) {
  int t = blockIdx.x * blockDim.x + threadIdx.x;
  if (t >= total) return;
  int s = t / (258 * 258);
  int rem = t - s * (258 * 258);
  int y = rem / 258, x = rem - y * 258;
  ushort4v v = {0, 0, 0, 0};
  if (y >= 1 && y <= 256 && x >= 1 && x <= 256) {
    const float* ip = img + ((size_t)(b0 + s) * 3) * 65536 + (y - 1) * 256 + (x - 1);
    v.x = f2bf(ip[0]);
    v.y = f2bf(ip[65536]);
    v.z = f2bf(ip[2 * 65536]);
  }
  *(ushort4v*)(dst + (size_t)t * 4) = v;
}

// zero halo of channels-last buffer [nsamp][HP][WP][IC]
template <int IC>
__global__ __launch_bounds__(256) void haloc_k(unsigned short* __restrict__ buf,
                                               int nsamp, int HP, int WP) {
  int per = 2 * WP + 2 * (HP - 2);
  int t = blockIdx.x * blockDim.x + threadIdx.x;
  if (t >= nsamp * per) return;
  int s = t / per, i = t - s * per;
  int y, x;
  if (i < WP) { y = 0; x = i; }
  else if (i < 2 * WP) { y = HP - 1; x = i - WP; }
  else {
    int ii = i - 2 * WP;
    y = 1 + (ii >> 1);
    x = (ii & 1) ? (WP - 1) : 0;
  }
  unsigned short* p = buf + ((size_t)s * HP * WP + y * WP + x) * IC;
  short8 z = {0, 0, 0, 0, 0, 0, 0, 0};
#pragma unroll
  for (int j = 0; j < IC / 8; ++j) ((short8*)p)[j] = z;
}

// conv1: 3->32, 256->128. imgp [258][258][4] c-last, K = 3 rows x 16.
// Wave = 64 px (4 n-tiles of 16). blockIdx.x = px block (256), .y = sample.
__global__ __launch_bounds__(256, 4) void conv1_k(
    const unsigned short* __restrict__ in, const unsigned short* __restrict__ wp,
    const float* __restrict__ bias, const int* __restrict__ rgn,
    unsigned short* __restrict__ outp, int b0) {
  const int tid = threadIdx.x;
  const int bl = blockIdx.y;
  const int r = __builtin_amdgcn_readfirstlane(rgn[b0 + bl]);
  __shared__ float sBias[32];
  if (tid < 32) sBias[tid] = bias[r * 32 + tid];
  __syncthreads();
  const int lane = tid & 63, n = tid & 15, q = (tid >> 4) & 3;
  const int px0 = (blockIdx.x * 4 + (tid >> 6)) * 64;
  const unsigned short* inb = in + (size_t)bl * 258 * 258 * 4 + (q & 1) * 8;
  int oyA[4], oxA[4];
  const unsigned short* pB[4];
#pragma unroll
  for (int nt = 0; nt < 4; ++nt) {
    int px = px0 + nt * 16 + n;
    oyA[nt] = px >> 7;
    oxA[nt] = px & 127;
    pB[nt] = inb + ((size_t)(2 * oyA[nt]) * 258 + 2 * oxA[nt]) * 4;
  }
  const short8* wpb = (const short8*)wp + (size_t)r * 256 + lane;
  floatx4 acc[4][2];
#pragma unroll
  for (int nt = 0; nt < 4; ++nt)
#pragma unroll
    for (int m = 0; m < 2; ++m) acc[nt][m] = (floatx4){0.f, 0.f, 0.f, 0.f};
#pragma unroll
  for (int kg = 0; kg < 2; ++kg) {
    int row = kg * 2 + (q >> 1);
    int rowc = (row < 3) ? row : 0;  // pad rows: zero weights, safe addr
    short8 bfr[4];
#pragma unroll
    for (int nt = 0; nt < 4; ++nt)
      bfr[nt] = *(const short8*)(pB[nt] + (size_t)rowc * 258 * 4);
    short8 afr[2];
#pragma unroll
    for (int m = 0; m < 2; ++m) afr[m] = wpb[(kg * 2 + m) * 64];
#pragma unroll
    for (int m = 0; m < 2; ++m)
#pragma unroll
      for (int nt = 0; nt < 4; ++nt)
        acc[nt][m] =
            __builtin_amdgcn_mfma_f32_16x16x32_bf16(afr[m], bfr[nt], acc[nt][m], 0, 0, 0);
  }
  unsigned short* ob = outp + (size_t)bl * 130 * 130 * 32;
#pragma unroll
  for (int nt = 0; nt < 4; ++nt)
#pragma unroll
    for (int m = 0; m < 2; ++m) {
      ushort4v st;
#pragma unroll
      for (int rr = 0; rr < 4; ++rr) {
        float v = acc[nt][m][rr] + sBias[m * 16 + q * 4 + rr];
        st[rr] = f2bf(v > 0.f ? v : 0.f);
      }
      *(ushort4v*)(ob + ((size_t)(oyA[nt] + 1) * 130 + oxA[nt] + 1) * 32 + m * 16 +
                   q * 4) = st;
    }
}

// per-tap MFMA conv, stride 2, channels-last, zero halo, 64 px/wave.
// blockIdx.x = px block (256), .y = oc-half, .z = sample. OCB = per-block oc.
template <int IC, int OCB, int OCTOT, int OW, int IWP, int SUBK, int OPW, bool GAP>
__global__ __launch_bounds__(256, 4) void convm_k(
    const unsigned short* __restrict__ in, const unsigned short* __restrict__ wp,
    const float* __restrict__ bias, const int* __restrict__ rgn,
    unsigned short* __restrict__ outp, float* __restrict__ feat, int b0) {
  constexpr int MT = OCB / 16;
  constexpr int MTG = OCTOT / 16;
  const int tid = threadIdx.x;
  const int bl = blockIdx.z;
  const int b = b0 + bl;
  const int r = __builtin_amdgcn_readfirstlane(rgn[b]);
  const int ocbase = blockIdx.y * OCB;
  __shared__ float sBias[OCB];
  for (int t = tid; t < OCB; t += 256) sBias[t] = bias[r * OCTOT + ocbase + t];
  __syncthreads();
  const int lane = tid & 63, n = tid & 15, q = (tid >> 4) & 3;
  const int px0 = (blockIdx.x * 4 + (tid >> 6)) * 64;
  const unsigned short* inS = in + (size_t)bl * IC * IWP * IWP + q * 8;
  int oyA[4], oxA[4];
  const unsigned short* pB[4];
#pragma unroll
  for (int nt = 0; nt < 4; ++nt) {
    int px = px0 + nt * 16 + n;
    oyA[nt] = px / OW;
    oxA[nt] = px % OW;
    pB[nt] = inS + ((size_t)(2 * oyA[nt]) * IWP + 2 * oxA[nt]) * IC;
  }
  const short8* wpb =
      (const short8*)wp + (size_t)r * 9 * SUBK * MTG * 64 + lane;
  floatx4 acc[4][MT];
#pragma unroll
  for (int nt = 0; nt < 4; ++nt)
#pragma unroll
    for (int m = 0; m < MT; ++m) acc[nt][m] = (floatx4){0.f, 0.f, 0.f, 0.f};
#pragma unroll
  for (int tap = 0; tap < 9; ++tap) {
    const int ky = tap / 3, kx = tap % 3;
#pragma unroll
    for (int s = 0; s < SUBK; ++s) {
      short8 bfr[4];
#pragma unroll
      for (int nt = 0; nt < 4; ++nt)
        bfr[nt] = *(const short8*)(pB[nt] + (size_t)(ky * IWP + kx) * IC + s * 32);
      short8 afr[MT];
#pragma unroll
      for (int m = 0; m < MT; ++m)
        afr[m] = wpb[((tap * SUBK + s) * MTG + blockIdx.y * MT + m) * 64];
#pragma unroll
      for (int m = 0; m < MT; ++m)
#pragma unroll
        for (int nt = 0; nt < 4; ++nt)
          acc[nt][m] = __builtin_amdgcn_mfma_f32_16x16x32_bf16(afr[m], bfr[nt],
                                                               acc[nt][m], 0, 0, 0);
    }
  }
  if constexpr (!GAP) {
    unsigned short* ob = outp + (size_t)bl * OCTOT * OPW * OPW;
#pragma unroll
    for (int nt = 0; nt < 4; ++nt)
#pragma unroll
      for (int m = 0; m < MT; ++m) {
        ushort4v st;
#pragma unroll
        for (int rr = 0; rr < 4; ++rr) {
          float v = acc[nt][m][rr] + sBias[m * 16 + q * 4 + rr];
          st[rr] = f2bf(v > 0.f ? v : 0.f);
        }
        *(ushort4v*)(ob + ((size_t)(oyA[nt] + 1) * OPW + oxA[nt] + 1) * OCTOT +
                     ocbase + m * 16 + q * 4) = st;
      }
  } else {
#pragma unroll
    for (int m = 0; m < MT; ++m)
#pragma unroll
      for (int rr = 0; rr < 4; ++rr) {
        float bv = sBias[m * 16 + q * 4 + rr];
        float vs = 0.f;
#pragma unroll
        for (int nt = 0; nt < 4; ++nt) {  // bias+ReLU per pixel, then presum
          float v = acc[nt][m][rr] + bv;
          vs += (v > 0.f ? v : 0.f);
        }
        vs += __shfl_xor(vs, 1, 16);
        vs += __shfl_xor(vs, 2, 16);
        vs += __shfl_xor(vs, 4, 16);
        vs += __shfl_xor(vs, 8, 16);
        if (n == 0)
          atomicAdd(&feat[b * 128 + ocbase + m * 16 + q * 4 + rr], vs);
      }
  }
}

__global__ __launch_bounds__(256) void head_k(
    const float* __restrict__ feat, const float* __restrict__ fw,
    const float* __restrict__ fb, const int* __restrict__ rgn,
    float* __restrict__ out) {
  int t = threadIdx.x;  // 128 samples x 2 classes
  int b = t >> 1, c = t & 1;
  int r = rgn[b];
  const float* fwr = fw + (r * 2 + c) * 128;
  const float* fv = feat + b * 128;
  float a = 0.f;
#pragma unroll 8
  for (int j = 0; j < 128; ++j) a = fmaf(fwr[j], fv[j], a);
  out[t] = a * (1.0f / 1024.0f) + fb[r * 2 + c];
}

extern "C" void kernel_launch(void* const* d_in, const int* in_sizes, int n_in,
                              void* d_out, int out_size, void* d_ws, size_t ws_size,
                              hipStream_t stream) {
  const float* img = (const float*)d_in[0];
  const int* rgn_raw = (const int*)d_in[1];
  const float* w1 = (const float*)d_in[2];
  const float* b1 = (const float*)d_in[3];
  const float* w2 = (const float*)d_in[4];
  const float* b2 = (const float*)d_in[5];
  const float* w3 = (const float*)d_in[6];
  const float* b3 = (const float*)d_in[7];
  const float* fw = (const float*)d_in[8];
  const float* fb = (const float*)d_in[9];
  float* out = (float*)d_out;

  const size_t imgp_s = (size_t)258 * 258 * 4 * 2;   // 532 KB
  const size_t h1p_s = (size_t)130 * 130 * 32 * 2;   // 1.08 MB
  const size_t h2p_s = (size_t)66 * 66 * 64 * 2;     // 557 KB
  const size_t per_sample = imgp_s + h1p_s + h2p_s;  // ~2.17 MB
  const size_t fixed = (size_t)16384 * 2 + (size_t)147456 * 2 +
                       (size_t)589824 * 2 + 128 * 128 * 4 + 512 + 16 * 256;
  int C = 128;
  while (C > 1 && fixed + (size_t)C * per_sample > ws_size) C >>= 1;

  char* ws = (char*)d_ws;
  size_t off = 0;
  auto alloc = [&](size_t bytes) {
    char* p = ws + off;
    off += (bytes + 255) & ~(size_t)255;
    return p;
  };
  unsigned short* imgp = (unsigned short*)alloc((size_t)C * imgp_s);
  unsigned short* h1p = (unsigned short*)alloc((size_t)C * h1p_s);
  unsigned short* h2p = (unsigned short*)alloc((size_t)C * h2p_s);
  unsigned short* w1p = (unsigned short*)alloc((size_t)16384 * 2);
  unsigned short* w2p = (unsigned short*)alloc((size_t)147456 * 2);
  unsigned short* w3p = (unsigned short*)alloc((size_t)589824 * 2);
  float* feat = (float*)alloc((size_t)128 * 128 * 4);
  int* rgn = (int*)alloc((size_t)128 * 4);

  hipLaunchKernelGGL(prep_k, dim3(1), dim3(128), 0, stream, rgn_raw, rgn, feat);
  hipLaunchKernelGGL(pack1_k, dim3(64), dim3(256), 0, stream, w1, w1p);
  hipLaunchKernelGGL((packT_k<64, 32, 1, 4>), dim3(576), dim3(256), 0, stream, w2, w2p);
  hipLaunchKernelGGL((packT_k<128, 64, 2, 8>), dim3(2304), dim3(256), 0, stream, w3, w3p);
  {  // zero halos once; interiors rewritten every chunk
    int n1 = C * (2 * 130 + 2 * 128);
    hipLaunchKernelGGL((haloc_k<32>), dim3((n1 + 255) / 256), dim3(256), 0, stream,
                       h1p, C, 130, 130);
    int n2 = C * (2 * 66 + 2 * 64);
    hipLaunchKernelGGL((haloc_k<64>), dim3((n2 + 255) / 256), dim3(256), 0, stream,
                       h2p, C, 66, 66);
  }

  for (int b0 = 0; b0 < 128; b0 += C) {
    int totimg = C * 258 * 258;
    hipLaunchKernelGGL(imgcvt_k, dim3((totimg + 255) / 256), dim3(256), 0, stream,
                       img, imgp, b0, totimg);
    hipLaunchKernelGGL(conv1_k, dim3(64, C), dim3(256), 0, stream,
                       imgp, w1p, b1, rgn, h1p, b0);
    // conv2: 4096 px / 256 per block = 16 x-blocks, all 64 oc per block
    hipLaunchKernelGGL((convm_k<32, 64, 64, 64, 130, 1, 66, false>),
                       dim3(16, 1, C), dim3(256), 0, stream,
                       h1p, w2p, b2, rgn, h2p, feat, b0);
    // conv3: 1024 px / 256 = 4 x-blocks, 2 oc-halves
    hipLaunchKernelGGL((convm_k<64, 64, 128, 32, 66, 2, 1, true>),
                       dim3(4, 2, C), dim3(256), 0, stream,
                       h2p, w3p, b3, rgn, (unsigned short*)nullptr, feat, b0);
  }
  hipLaunchKernelGGL(head_k, dim3(1), dim3(256), 0, stream, feat, fw, fb, rgn, out);
}